// Round 10
// baseline (448.140 us; speedup 1.0000x reference)
//
#include <hip/hip_runtime.h>
#include <stdint.h>

#define M_TOK 256
#define K_IN  4096
#define KP    512               // K_IN/8 packed uint32 per row
#define N_OUT 11008
#define K_EXT 4160              // 4096 + 16 lora + 48 zero pad
#define ROWB  (K_EXT * 2)       // bytes per x_ext row = 8320
#define BM    64
#define BN    64
#define NGL   172               // 11008 / 64
#define GRID  (4 * 4 * NGL)     // 2752 = 8 xcd * 344
#define PW_OFF (4u << 20)       // pw at d_ws + 4 MB (xe occupies first ~2.1 MB)

typedef __attribute__((ext_vector_type(8))) short s16x8;
typedef __attribute__((ext_vector_type(8))) unsigned short u16x8;
typedef __attribute__((ext_vector_type(4))) float f32x4;

#define VMW(n)   asm volatile("s_waitcnt vmcnt(" #n ")" ::: "memory")
#define SCHED0() __builtin_amdgcn_sched_barrier(0)

static __device__ __forceinline__ unsigned cvt_pk_bf16(float lo, float hi) {
  unsigned r;
  asm("v_cvt_pk_bf16_f32 %0, %1, %2" : "=v"(r) : "v"(lo), "v"(hi));
  return r;
}

__device__ __forceinline__ unsigned short f2bf(float f) {
  union { float f; unsigned int u; } v; v.f = f;
  unsigned int u = v.u;
  u += 0x7fffu + ((u >> 16) & 1u);   // RNE
  return (unsigned short)(u >> 16);
}

// ---- repack: qweight int32(0..15) -> packed nibbles, 8 k per uint32 ----
// 5,636,096 outputs; 1 per thread; reads 2x dwordx4, writes 1 dword.
__global__ __launch_bounds__(256) void repack_kernel(
    const int* __restrict__ qw, unsigned* __restrict__ pw)
{
  const unsigned i = blockIdx.x * 256 + threadIdx.x;   // output u32 index
  const int* p = qw + (size_t)i * 8;
  const int4 a = *(const int4*)(p);
  const int4 b = *(const int4*)(p + 4);
  unsigned u = (unsigned)(a.x & 15)
             | ((unsigned)(a.y & 15) << 4)
             | ((unsigned)(a.z & 15) << 8)
             | ((unsigned)(a.w & 15) << 12)
             | ((unsigned)(b.x & 15) << 16)
             | ((unsigned)(b.y & 15) << 20)
             | ((unsigned)(b.z & 15) << 24)
             | ((unsigned)(b.w & 15) << 28);
  pw[i] = u;
}

// ---- prep: x fp32 -> bf16 row (stride K_EXT) + lora t2 appended as cols 4096.. ----
__global__ __launch_bounds__(512) void prep_kernel(
    const float* __restrict__ x, const float* __restrict__ la,
    unsigned short* __restrict__ xe)
{
  const int m   = blockIdx.x;
  const int tid = threadIdx.x;
  const int k   = tid * 8;
  const float* xr = x + (size_t)m * K_IN;
  unsigned short* xer = xe + (size_t)m * K_EXT;

  const float4 f0 = *(const float4*)(xr + k);
  const float4 f1 = *(const float4*)(xr + k + 4);
  u16x8 o;
  o[0] = f2bf(f0.x); o[1] = f2bf(f0.y); o[2] = f2bf(f0.z); o[3] = f2bf(f0.w);
  o[4] = f2bf(f1.x); o[5] = f2bf(f1.y); o[6] = f2bf(f1.z); o[7] = f2bf(f1.w);
  *(u16x8*)(xer + k) = o;

  if (tid >= 464) xer[K_IN + 16 + (tid - 464)] = 0;   // zero pad cols 4112..4159

  const int wave = tid >> 6, lane = tid & 63;
  const float* a0p = la + (size_t)(wave * 2) * K_IN;
  const float* a1p = a0p + K_IN;
  float s0 = 0.f, s1 = 0.f;
  #pragma unroll 4
  for (int it = 0; it < 16; ++it) {
    const int kk = it * 256 + lane * 4;
    const float4 xv = *(const float4*)(xr + kk);
    const float4 a0 = *(const float4*)(a0p + kk);
    const float4 a1 = *(const float4*)(a1p + kk);
    s0 += xv.x * a0.x + xv.y * a0.y + xv.z * a0.z + xv.w * a0.w;
    s1 += xv.x * a1.x + xv.y * a1.y + xv.z * a1.z + xv.w * a1.w;
  }
  #pragma unroll
  for (int off = 32; off > 0; off >>= 1) {
    s0 += __shfl_down(s0, off);
    s1 += __shfl_down(s1, off);
  }
  if (lane == 0) {
    xer[K_IN + wave * 2]     = f2bf(2.0f * s0);   // SCALING folded
    xer[K_IN + wave * 2 + 1] = f2bf(2.0f * s1);
  }
}

// ---------------- main: barrier-free split-K GEMM, nibble weights ----------------
// 2752 blocks x 256 threads (4 waves, 2x2 wave-tiles of 32x32), K/4 per block.
// B: one uint32 of packed nibbles per MFMA fragment, dequant in registers.
// A: x in wave-private LDS via global_load_lds (stager == reader -> no barrier).
// ZERO barriers; counted vmcnt only.  XCD-correct tile mapping (qw/pw L2-local).
__global__ __launch_bounds__(256, 4) void gptq_lora_gemm(
    const unsigned* __restrict__ pw, const float* __restrict__ sc,
    const int* __restrict__ zr, const float* __restrict__ lb,
    const unsigned short* __restrict__ xe, float* __restrict__ out)
{
  __shared__ unsigned short xs[2][4][32 * 64];   // [buf][wave][rows 32][k 64], 32 KB

  const int tid  = threadIdx.x;
  const int wave = tid >> 6;
  const int lane = tid & 63;

  // XCD-aware decomposition (round-robin xcd = bid % 8)
  const int bid  = blockIdx.x;
  const int xcd  = bid & 7;
  const int r    = bid >> 3;
  const int mg   = r & 3;
  const int tIdx = r >> 2;
  const int tile = xcd * 86 + tIdx;   // 0..687
  const int kq   = tile & 3;
  const int ngl  = tile >> 2;
  const int m0   = mg * BM;
  const int n0   = ngl * BN;

  const int wm = wave >> 1;
  const int wn = wave & 1;

  const int alo   = lane & 15;
  const int kb_hi = (lane >> 4) * 16;   // byte offset in 128B row slice
  const int koff  = (lane >> 4) * 8;    // k offset for B fragment

  const int n0c = n0 + wn * 32 + alo;   // B col, nf=0
  const int n1c = n0c + 16;             // B col, nf=1
  const unsigned* pwq0 = pw + (size_t)n0c * KP + (koff >> 3);
  const unsigned* pwq1 = pw + (size_t)n1c * KP + (koff >> 3);
  const float* scp0 = sc + (size_t)n0c * 32;
  const float* scp1 = sc + (size_t)n1c * 32;
  const int*   zrp0 = zr + (size_t)n0c * 32;
  const int*   zrp1 = zr + (size_t)n1c * 32;

  f32x4 acc[2][2];
  #pragma unroll
  for (int i = 0; i < 2; ++i) { acc[i][0] = (f32x4)0.f; acc[i][1] = (f32x4)0.f; }

  s16x8 bbv[4];     // [0]=nf0ks0 [1]=nf0ks1 [2]=nf1ks0 [3]=nf1ks1
  union BBu { s16x8 v; unsigned u[4]; };

  const char* xb = (const char*)xe;
  const int gm0 = m0 + wm * 32;         // this wave's 32 x-rows

  auto stage_x = [&](int buf, int step) {          // 4 glds, wave-private
    #pragma unroll
    for (int i = 0; i < 4; ++i) {
      const int basel = i * 1024;
      const int o     = basel + lane * 16;
      const int mrow  = o >> 7;                    // 0..31
      const int kb    = o & 127;
      const char* src = xb + (size_t)(gm0 + mrow) * ROWB + step * 128
                           + (kb ^ ((mrow & 7) << 4));
      __builtin_amdgcn_global_load_lds(
          (const __attribute__((address_space(1))) void*)src,
          (__attribute__((address_space(3))) void*)((char*)&xs[buf][wave][0] + basel),
          16, 0, 0);
    }
  };

  // dequant one packed u32 (8 nibbles) -> 8 bf16 fragment
  auto dq32 = [&](unsigned p, float s, float nz, s16x8& dst) {
    BBu b;
    #pragma unroll
    for (int h = 0; h < 4; ++h) {
      const float lo = fmaf((float)((p >> (8 * h)) & 15u), s, nz);
      const float hi = fmaf((float)((p >> (8 * h + 4)) & 15u), s, nz);
      b.u[h] = cvt_pk_bf16(lo, hi);
    }
    dst = b.v;
  };

  auto compute = [&](int buf) {
    const char* xbase = (const char*)&xs[buf][wave][0];
    #pragma unroll
    for (int mf = 0; mf < 2; ++mf) {
      const int rl  = mf * 16 + alo;               // 0..31
      const int swz = (rl & 7) << 4;
      const s16x8 af0 = *(const s16x8*)(xbase + rl * 128 + (kb_hi ^ swz));
      const s16x8 af1 = *(const s16x8*)(xbase + rl * 128 + ((64 + kb_hi) ^ swz));
      acc[mf][0] = __builtin_amdgcn_mfma_f32_16x16x32_bf16(af0, bbv[0], acc[mf][0], 0, 0, 0);
      acc[mf][0] = __builtin_amdgcn_mfma_f32_16x16x32_bf16(af1, bbv[1], acc[mf][0], 0, 0, 0);
      acc[mf][1] = __builtin_amdgcn_mfma_f32_16x16x32_bf16(af0, bbv[2], acc[mf][1], 0, 0, 0);
      acc[mf][1] = __builtin_amdgcn_mfma_f32_16x16x32_bf16(af1, bbv[3], acc[mf][1], 0, 0, 0);
    }
  };

  // pw register sets A/B (static names; no dynamic indexing)
  unsigned qa0, qa1, qa2, qa3, qb0, qb1, qb2, qb3;
  float    sa0, sa1, sb0, sb1;
  int      za0, za1, zb0, zb1;

  #define LOADPW_A(t) { const int _o = (t) * 8, _g = (t) >> 1;              \
    qa0 = pwq0[_o]; qa1 = pwq0[_o + 4]; qa2 = pwq1[_o]; qa3 = pwq1[_o + 4]; \
    sa0 = scp0[_g]; za0 = zrp0[_g]; sa1 = scp1[_g]; za1 = zrp1[_g]; }
  #define LOADPW_B(t) { const int _o = (t) * 8, _g = (t) >> 1;              \
    qb0 = pwq0[_o]; qb1 = pwq0[_o + 4]; qb2 = pwq1[_o]; qb3 = pwq1[_o + 4]; \
    sb0 = scp0[_g]; zb0 = zrp0[_g]; sb1 = scp1[_g]; zb1 = zrp1[_g]; }
  #define DEQ_A() { const float nz0 = -(float)za0 * sa0, nz1 = -(float)za1 * sa1; \
    dq32(qa0, sa0, nz0, bbv[0]); dq32(qa1, sa0, nz0, bbv[1]);                     \
    dq32(qa2, sa1, nz1, bbv[2]); dq32(qa3, sa1, nz1, bbv[3]); }
  #define DEQ_B() { const float nz0 = -(float)zb0 * sb0, nz1 = -(float)zb1 * sb1; \
    dq32(qb0, sb0, nz0, bbv[0]); dq32(qb1, sb0, nz0, bbv[1]);                     \
    dq32(qb2, sb1, nz1, bbv[2]); dq32(qb3, sb1, nz1, bbv[3]); }

  const int tbase = kq * 16;

  // ---- prologue ----
  LOADPW_A(tbase);          // 8 vm
  SCHED0();
  stage_x(0, tbase);        // 4 glds
  SCHED0();
  LOADPW_B(tbase + 1);      // 8 vm
  SCHED0();
  VMW(12); SCHED0();        // pwA ready (newer: 4 glds + 8)
  DEQ_A();                  // frags B(tbase)

  // ---- uniform barrier-free loop: 14 steps, 7 unrolled pairs ----
  int bufx = 0;
  #pragma unroll 1
  for (int tp = 0; tp < 7; ++tp) {
    const int t = tbase + tp * 2;
    // step t: consume frags(t); next frags from pwB; load pwA(t+2)
    stage_x(bufx ^ 1, t + 1); SCHED0();
    LOADPW_A(t + 2); SCHED0();
    VMW(20); SCHED0();        // x(t) ready (newer: 8 + 4 + 8)
    compute(bufx);
    VMW(12); SCHED0();        // pwB(t+1) ready (newer: 4 + 8)
    DEQ_B();
    bufx ^= 1;
    // step t+1: consume frags(t+1); load pwB(t+3)
    stage_x(bufx ^ 1, t + 2); SCHED0();
    LOADPW_B(t + 3); SCHED0();
    VMW(20); SCHED0();
    compute(bufx);
    VMW(12); SCHED0();        // pwA(t+2) ready
    DEQ_A();
    bufx ^= 1;
  }

  const int t14 = tbase + 14;
  const int t15 = tbase + 15;

  if (kq < 3) {
    // ---- peel t14 ----
    stage_x(bufx ^ 1, t15); SCHED0();
    VMW(12); SCHED0();        // x(t14) (newer: prev 8 + 4)
    compute(bufx);
    VMW(4); SCHED0();         // pwB(t15) (newer: 4 glds)
    DEQ_B();
    bufx ^= 1;
    // ---- peel t15 ----
    VMW(0); SCHED0();
    compute(bufx);
  } else {
    // ---- peel t14 (=62): also load lora-B floats ----
    stage_x(bufx ^ 1, 63); SCHED0();
    const int koffc = (koff < 16) ? koff : 0;
    const float* lbp0 = lb + (size_t)n0c * 16 + koffc;
    const float* lbp1 = lb + (size_t)n1c * 16 + koffc;
    float4 tl0, tl1, tl2, tl3;
    tl0 = *(const float4*)(lbp0);
    tl1 = *(const float4*)(lbp0 + 4);
    tl2 = *(const float4*)(lbp1);
    tl3 = *(const float4*)(lbp1 + 4);
    SCHED0();
    VMW(16); SCHED0();        // x(62) (newer: 8 + 4 + 4)
    compute(bufx);
    VMW(8); SCHED0();         // pwB(63) (newer: 4 glds + 4 lora)
    DEQ_B();
    bufx ^= 1;
    // ---- peel t15 (=63): stage lora x columns ----
    stage_x(bufx ^ 1, 64); SCHED0();
    VMW(8); SCHED0();         // x(63) (newer: 4 lora + 4 glds)
    compute(bufx);
    VMW(4); SCHED0();         // lora floats (newer: 4 glds)
    {
      const bool valid = (lane < 32);
      BBu b0, b1, z;
      b0.u[0] = valid ? cvt_pk_bf16(tl0.x, tl0.y) : 0u;
      b0.u[1] = valid ? cvt_pk_bf16(tl0.z, tl0.w) : 0u;
      b0.u[2] = valid ? cvt_pk_bf16(tl1.x, tl1.y) : 0u;
      b0.u[3] = valid ? cvt_pk_bf16(tl1.z, tl1.w) : 0u;
      b1.u[0] = valid ? cvt_pk_bf16(tl2.x, tl2.y) : 0u;
      b1.u[1] = valid ? cvt_pk_bf16(tl2.z, tl2.w) : 0u;
      b1.u[2] = valid ? cvt_pk_bf16(tl3.x, tl3.y) : 0u;
      b1.u[3] = valid ? cvt_pk_bf16(tl3.z, tl3.w) : 0u;
      z.u[0] = 0; z.u[1] = 0; z.u[2] = 0; z.u[3] = 0;
      bbv[0] = b0.v; bbv[1] = z.v; bbv[2] = b1.v; bbv[3] = z.v;
    }
    bufx ^= 1;
    // ---- peel t16 (=64): lora columns (k-local 32..63 zero both sides) ----
    VMW(0); SCHED0();
    compute(bufx);
  }

  // ---- epilogue: atomic combine of split-K partials ----
  const int rb = m0 + wm * 32 + (lane >> 4) * 4;
  const int cb = n0 + wn * 32 + alo;
  #pragma unroll
  for (int mf = 0; mf < 2; ++mf) {
    #pragma unroll
    for (int nf = 0; nf < 2; ++nf) {
      #pragma unroll
      for (int j = 0; j < 4; ++j) {
        atomicAdd(&out[(size_t)(rb + mf * 16 + j) * N_OUT + (cb + nf * 16)],
                  acc[mf][nf][j]);
      }
    }
  }
  #undef LOADPW_A
  #undef LOADPW_B
  #undef DEQ_A
  #undef DEQ_B
}

extern "C" void kernel_launch(void* const* d_in, const int* in_sizes, int n_in,
                              void* d_out, int out_size, void* d_ws, size_t ws_size,
                              hipStream_t stream) {
  const float* x  = (const float*)d_in[0];
  const int*   qw = (const int*)d_in[1];
  const float* sc = (const float*)d_in[2];
  const int*   zr = (const int*)d_in[3];
  const float* la = (const float*)d_in[4];
  const float* lb = (const float*)d_in[5];
  float* out = (float*)d_out;
  unsigned short* xe = (unsigned short*)d_ws;                    // 2.13 MB
  unsigned* pwp = (unsigned*)((char*)d_ws + PW_OFF);             // 22.5 MB

  hipMemsetAsync(d_out, 0, (size_t)out_size * sizeof(float), stream);
  repack_kernel<<<(N_OUT * KP) / 256, 256, 0, stream>>>(qw, pwp);
  prep_kernel<<<M_TOK, 512, 0, stream>>>(x, la, xe);
  gptq_lora_gemm<<<GRID, 256, 0, stream>>>(pwp, sc, zr, lb, xe, out);
}

// Round 11
// 364.363 us; speedup vs baseline: 1.2299x; 1.2299x over previous
//
#include <hip/hip_runtime.h>
#include <stdint.h>

#define M_TOK 256
#define K_IN  4096
#define KP2   256               // uint2 (8B) per row = K_IN/16
#define N_OUT 11008
#define K_EXT 4160              // 4096 + 16 lora + 48 zero pad
#define ROWB  (K_EXT * 2)       // bytes per x_ext row = 8320
#define BM    32
#define BN    64
#define NGL   172               // 11008 / 64
#define GRID  (8 * NGL)         // 1376 blocks per K-half launch
#define PW_OFF (4u << 20)       // pw at d_ws + 4 MB

typedef __attribute__((ext_vector_type(8))) short s16x8;
typedef __attribute__((ext_vector_type(8))) unsigned short u16x8;
typedef __attribute__((ext_vector_type(4))) float f32x4;

static __device__ __forceinline__ unsigned cvt_pk_bf16(float lo, float hi) {
  unsigned r;
  asm("v_cvt_pk_bf16_f32 %0, %1, %2" : "=v"(r) : "v"(lo), "v"(hi));
  return r;
}

__device__ __forceinline__ unsigned short f2bf(float f) {
  union { float f; unsigned int u; } v; v.f = f;
  unsigned int u = v.u;
  u += 0x7fffu + ((u >> 16) & 1u);   // RNE
  return (unsigned short)(u >> 16);
}

// ---- repack: qweight int32(0..15) -> packed nibbles, 8 k per uint32 ----
__global__ __launch_bounds__(256) void repack_kernel(
    const int* __restrict__ qw, unsigned* __restrict__ pw)
{
  const unsigned i = blockIdx.x * 256 + threadIdx.x;
  const int* p = qw + (size_t)i * 8;
  const int4 a = *(const int4*)(p);
  const int4 b = *(const int4*)(p + 4);
  unsigned u = (unsigned)(a.x & 15)
             | ((unsigned)(a.y & 15) << 4)
             | ((unsigned)(a.z & 15) << 8)
             | ((unsigned)(a.w & 15) << 12)
             | ((unsigned)(b.x & 15) << 16)
             | ((unsigned)(b.y & 15) << 20)
             | ((unsigned)(b.z & 15) << 24)
             | ((unsigned)(b.w & 15) << 28);
  pw[i] = u;
}

// ---- prep: x fp32 -> bf16 row (stride K_EXT) + lora t2 appended as cols 4096.. ----
__global__ __launch_bounds__(512) void prep_kernel(
    const float* __restrict__ x, const float* __restrict__ la,
    unsigned short* __restrict__ xe)
{
  const int m   = blockIdx.x;
  const int tid = threadIdx.x;
  const int k   = tid * 8;
  const float* xr = x + (size_t)m * K_IN;
  unsigned short* xer = xe + (size_t)m * K_EXT;

  const float4 f0 = *(const float4*)(xr + k);
  const float4 f1 = *(const float4*)(xr + k + 4);
  u16x8 o;
  o[0] = f2bf(f0.x); o[1] = f2bf(f0.y); o[2] = f2bf(f0.z); o[3] = f2bf(f0.w);
  o[4] = f2bf(f1.x); o[5] = f2bf(f1.y); o[6] = f2bf(f1.z); o[7] = f2bf(f1.w);
  *(u16x8*)(xer + k) = o;

  if (tid >= 464) xer[K_IN + 16 + (tid - 464)] = 0;   // zero cols 4112..4159

  const int wave = tid >> 6, lane = tid & 63;
  const float* a0p = la + (size_t)(wave * 2) * K_IN;
  const float* a1p = a0p + K_IN;
  float s0 = 0.f, s1 = 0.f;
  #pragma unroll 4
  for (int it = 0; it < 16; ++it) {
    const int kk = it * 256 + lane * 4;
    const float4 xv = *(const float4*)(xr + kk);
    const float4 a0 = *(const float4*)(a0p + kk);
    const float4 a1 = *(const float4*)(a1p + kk);
    s0 += xv.x * a0.x + xv.y * a0.y + xv.z * a0.z + xv.w * a0.w;
    s1 += xv.x * a1.x + xv.y * a1.y + xv.z * a1.z + xv.w * a1.w;
  }
  #pragma unroll
  for (int off = 32; off > 0; off >>= 1) {
    s0 += __shfl_down(s0, off);
    s1 += __shfl_down(s1, off);
  }
  if (lane == 0) {
    xer[K_IN + wave * 2]     = f2bf(2.0f * s0);   // SCALING folded
    xer[K_IN + wave * 2 + 1] = f2bf(2.0f * s1);
  }
}

// ---------------- main: K-half GEMM, barrier dbuf, nibble dequant ----------------
// PHASE 0: steps 0..31, out = partial.  PHASE 1: steps 32..63 + lora, out += partial.
// BM=32 x BN=64, BK=64; 256 threads (4 waves, wave-tile 16x32). LDS 24 KB.
// mg-major bids: the 8 m-sharers of a pw tile land on 2 XCDs.
template <int PHASE>
__global__ __launch_bounds__(256, 6) void gptq_lora_gemm(
    const unsigned* __restrict__ pw, const float* __restrict__ sc,
    const int* __restrict__ zr, const float* __restrict__ lb,
    const unsigned short* __restrict__ xe, float* __restrict__ out)
{
  __shared__ unsigned short xs[2][BM * 64];   // 2 x 4 KB, XOR-swizzled rows
  __shared__ unsigned short wt[2][BN * 64];   // 2 x 8 KB, XOR-swizzled rows

  const int tid  = threadIdx.x;
  const int wave = tid >> 6;
  const int lane = tid & 63;

  const int bid = blockIdx.x;
  const int mg  = bid / NGL;        // 0..7 (mg-major: sharers 172 bids apart)
  const int ngl = bid - mg * NGL;   // 0..171
  const int m0  = mg * BM;
  const int n0  = ngl * BN;

  const int wm = wave >> 1;         // 0..1 : 16 m-rows
  const int wn = wave & 1;          // 0..1 : 32 n-cols

  const int alo   = lane & 15;
  const int kb_hi = (lane >> 4) * 16;

  // W-staging: row sn (0..63), j = k-16-block (0..3)
  const int sn  = tid >> 2;
  const int j   = tid & 3;
  const int n_glob = n0 + sn;
  const int swz_s  = (sn & 7) << 4;
  const int wt_o0  = sn * 128 + ((j * 32) ^ swz_s);
  const int wt_o1  = sn * 128 + ((j * 32 + 16) ^ swz_s);
  const uint2* pwp = (const uint2*)pw + (size_t)n_glob * KP2 + j;   // + t*4
  const float* scp = sc + (size_t)n_glob * 32;
  const int*   zrp = zr + (size_t)n_glob * 32;

  f32x4 acc[2];
  acc[0] = (f32x4)0.f; acc[1] = (f32x4)0.f;

  const char* xb = (const char*)xe;

  auto stage_x = [&](int buf, int t) {           // 1 glds per wave (1 KB)
    const int base = wave * 1024;
    const int o    = base + lane * 16;
    const int mrow = o >> 7;                     // wave*8 + (lane>>3)
    const int kb   = o & 127;
    const char* src = xb + (size_t)(m0 + mrow) * ROWB + t * 128
                         + (kb ^ ((mrow & 7) << 4));
    __builtin_amdgcn_global_load_lds(
        (const __attribute__((address_space(1))) void*)src,
        (__attribute__((address_space(3))) void*)((char*)xs[buf] + base),
        16, 0, 0);
  };

  struct Stg { uint2 q; float s, z; float4 f; };

  auto loadS = [&](int t, Stg& g) {
    if (!PHASE || t < 64) {
      g.q = pwp[t * 4];                          // dwordx2, coalesced
      const int grp = t >> 1;
      g.s = scp[grp];
      g.z = (float)zrp[grp];
    } else {                                     // lora tail (phase 1 only)
      g.f = *(const float4*)(lb + (size_t)n_glob * 16 + j * 4);
    }
  };

  auto writeS = [&](int buf, int t, const Stg& g) {
    if (!PHASE || t < 64) {
      const float s = g.s, nz = -g.z * g.s;
      int4 pk0, pk1;
      pk0.x = (int)(cvt_pk_bf16(fmaf((float)((g.q.x      ) & 15u), s, nz),
                                fmaf((float)((g.q.x >>  4) & 15u), s, nz)));
      pk0.y = (int)(cvt_pk_bf16(fmaf((float)((g.q.x >>  8) & 15u), s, nz),
                                fmaf((float)((g.q.x >> 12) & 15u), s, nz)));
      pk0.z = (int)(cvt_pk_bf16(fmaf((float)((g.q.x >> 16) & 15u), s, nz),
                                fmaf((float)((g.q.x >> 20) & 15u), s, nz)));
      pk0.w = (int)(cvt_pk_bf16(fmaf((float)((g.q.x >> 24) & 15u), s, nz),
                                fmaf((float)((g.q.x >> 28) & 15u), s, nz)));
      pk1.x = (int)(cvt_pk_bf16(fmaf((float)((g.q.y      ) & 15u), s, nz),
                                fmaf((float)((g.q.y >>  4) & 15u), s, nz)));
      pk1.y = (int)(cvt_pk_bf16(fmaf((float)((g.q.y >>  8) & 15u), s, nz),
                                fmaf((float)((g.q.y >> 12) & 15u), s, nz)));
      pk1.z = (int)(cvt_pk_bf16(fmaf((float)((g.q.y >> 16) & 15u), s, nz),
                                fmaf((float)((g.q.y >> 20) & 15u), s, nz)));
      pk1.w = (int)(cvt_pk_bf16(fmaf((float)((g.q.y >> 24) & 15u), s, nz),
                                fmaf((float)((g.q.y >> 28) & 15u), s, nz)));
      *(int4*)((char*)wt[buf] + wt_o0) = pk0;
      *(int4*)((char*)wt[buf] + wt_o1) = pk1;
    } else {
      // lora: k-local 0..15 = B values; k>=16 left stale (finite) -- x pad is 0.
      int2 pk;
      pk.x = (int)cvt_pk_bf16(g.f.x, g.f.y);
      pk.y = (int)cvt_pk_bf16(g.f.z, g.f.w);
      *(int2*)((char*)wt[buf] + sn * 128 + ((j * 8) ^ swz_s)) = pk;
    }
  };

  auto compute = [&](int buf) {
    s16x8 bfr[2][2];
    #pragma unroll
    for (int nf = 0; nf < 2; ++nf) {
      const int c   = wn * 32 + nf * 16 + alo;
      const int swz = (c & 7) << 4;
      #pragma unroll
      for (int ks = 0; ks < 2; ++ks)
        bfr[nf][ks] = *(const s16x8*)((const char*)wt[buf] + c * 128 + ((ks * 64 + kb_hi) ^ swz));
    }
    const int r   = wm * 16 + alo;
    const int swz = (r & 7) << 4;
    const s16x8 af0 = *(const s16x8*)((const char*)xs[buf] + r * 128 + (kb_hi ^ swz));
    const s16x8 af1 = *(const s16x8*)((const char*)xs[buf] + r * 128 + ((64 + kb_hi) ^ swz));
    acc[0] = __builtin_amdgcn_mfma_f32_16x16x32_bf16(af0, bfr[0][0], acc[0], 0, 0, 0);
    acc[0] = __builtin_amdgcn_mfma_f32_16x16x32_bf16(af1, bfr[0][1], acc[0], 0, 0, 0);
    acc[1] = __builtin_amdgcn_mfma_f32_16x16x32_bf16(af0, bfr[1][0], acc[1], 0, 0, 0);
    acc[1] = __builtin_amdgcn_mfma_f32_16x16x32_bf16(af1, bfr[1][1], acc[1], 0, 0, 0);
  };

  const int tbase  = PHASE ? 32 : 0;
  const int nsteps = PHASE ? 33 : 32;   // phase1: +1 lora tail step (t=64)

  // ---- prologue ----
  {
    Stg g;
    loadS(tbase, g);
    stage_x(0, tbase);
    writeS(0, tbase, g);
  }
  __syncthreads();

  // ---- dbuf loop: loads early, dequant after compute, 1 barrier/step ----
  int b = 0;
  #pragma unroll 1
  for (int i = 0; i < nsteps; ++i) {
    const int t = tbase + i;
    const bool more = (i + 1 < nsteps);
    Stg g;
    if (more) {
      loadS(t + 1, g);          // global -> regs (latency under compute)
      stage_x(b ^ 1, t + 1);    // async glds
    }
    compute(b);                 // 6 ds_read_b128 + 4 MFMA
    if (more) writeS(b ^ 1, t + 1, g);
    __syncthreads();
    b ^= 1;
  }

  // ---- epilogue: phase0 stores, phase1 accumulates (race-free: 1 owner/elem) ----
  const int rb = m0 + wm * 16 + (lane >> 4) * 4;
  const int cb = n0 + wn * 32 + alo;
  #pragma unroll
  for (int nf = 0; nf < 2; ++nf) {
    #pragma unroll
    for (int jj = 0; jj < 4; ++jj) {
      float* p = out + (size_t)(rb + jj) * N_OUT + (cb + nf * 16);
      if (PHASE == 0) *p = acc[nf][jj];
      else            *p += acc[nf][jj];
    }
  }
}

extern "C" void kernel_launch(void* const* d_in, const int* in_sizes, int n_in,
                              void* d_out, int out_size, void* d_ws, size_t ws_size,
                              hipStream_t stream) {
  const float* x  = (const float*)d_in[0];
  const int*   qw = (const int*)d_in[1];
  const float* sc = (const float*)d_in[2];
  const int*   zr = (const int*)d_in[3];
  const float* la = (const float*)d_in[4];
  const float* lb = (const float*)d_in[5];
  float* out = (float*)d_out;
  unsigned short* xe = (unsigned short*)d_ws;                 // 2.13 MB
  unsigned* pwp = (unsigned*)((char*)d_ws + PW_OFF);          // 22.5 MB

  repack_kernel<<<(N_OUT * (K_IN / 8)) / 256, 256, 0, stream>>>(qw, pwp);
  prep_kernel<<<M_TOK, 512, 0, stream>>>(x, la, xe);
  gptq_lora_gemm<0><<<GRID, 256, 0, stream>>>(pwp, sc, zr, lb, xe, out);
  gptq_lora_gemm<1><<<GRID, 256, 0, stream>>>(pwp, sc, zr, lb, xe, out);
}